// Round 5
// baseline (161.276 us; speedup 1.0000x reference)
//
#include <hip/hip_runtime.h>
#include <math.h>

#define Bb 8
#define Tt 2048
#define Cc 1024
#define Hh 64

typedef __attribute__((ext_vector_type(8))) short short8;
typedef __attribute__((ext_vector_type(4))) float f32x4;

// float -> bf16 bits, round-to-nearest-even (scalar path)
static __device__ __forceinline__ unsigned short f2bf(float f) {
    union { float f; unsigned u; } v; v.f = f;
    return (unsigned short)((v.u + 0x7FFFu + ((v.u >> 16) & 1u)) >> 16);
}
// pack 2 f32 -> 2 bf16 in one instr (no builtin on gfx950; RNE, matches f2bf)
static __device__ __forceinline__ unsigned pack2(float lo, float hi) {
    unsigned r;
    asm("v_cvt_pk_bf16_f32 %0, %1, %2" : "=v"(r) : "v"(lo), "v"(hi));
    return r;
}

#define LOG2E 1.44269504088896340736f

// ---------------------------------------------------------------------------
// Kernel 1: W -> bf16, transposed [192][1024].  n 0-63 = Wq*(0.125*log2e),
// 64-127 = Wk, 128-191 = Wv.
// ---------------------------------------------------------------------------
__global__ __launch_bounds__(256)
void wconv_kernel(const float* __restrict__ Wk, const float* __restrict__ Wq,
                  const float* __restrict__ Wv, unsigned short* __restrict__ WbT)
{
    const int n = blockIdx.x;            // 0..191
    const int h = n & 63;
    const float* W; float scale = 1.0f;
    if (n < 64)       { W = Wq; scale = 0.125f * LOG2E; }
    else if (n < 128) { W = Wk; }
    else              { W = Wv; }
    #pragma unroll
    for (int i = 0; i < 4; ++i) {
        const int k = threadIdx.x + (i << 8);
        WbT[n * 1024 + k] = f2bf(W[k * 64 + h] * scale);
    }
}

// ---------------------------------------------------------------------------
// Kernel 2: QKV projection, bf16 MFMA, NO B-LDS.
// [16384,1024] x [1024,192], tile 32(M) x 192(N), K-step 64, grid 512.
// 4 waves col-split (wave w owns cols w*48..w*48+47) -> B elements are
// wave-private, so B-frags load DIRECTLY from L2 (WbT hot, 64B granules:
// 4 fko-lanes x 16B per row).  Only A (32x64 bf16, 4.6 KB) goes through LDS,
// reg-prefetched across the barrier; fp32->bf16 via v_cvt_pk_bf16_f32.
// v written transposed to vt[b][h][t] from the epilogue.
// ---------------------------------------------------------------------------
__global__ __launch_bounds__(256)
void proj_kernel(const float* __restrict__ x, const unsigned short* __restrict__ WbT,
                 unsigned short* __restrict__ qb, unsigned short* __restrict__ kb,
                 unsigned short* __restrict__ vt)
{
    __shared__ unsigned short As[32][72];

    const int tid  = threadIdx.x;
    const int row0 = blockIdx.x * 32;
    const int lane = tid & 63;
    const int w    = tid >> 6;           // 0..3 -> N offset w*48
    const int fr   = lane & 15;
    const int fg   = lane >> 4;          // 0..3
    const int fko  = fg << 3;

    // A-stage addressing: thread owns row ar, 8 floats at col ac (+64 per step)
    const int ar = tid >> 3;             // 0..31
    const int ac = (tid & 7) << 3;       // 0..56
    const float* xrow = &x[(size_t)(row0 + ar) * Cc + ac];

    // B row bases (wave-private cols)
    const unsigned short* Brow[3];
    #pragma unroll
    for (int nf = 0; nf < 3; ++nf)
        Brow[nf] = &WbT[(size_t)(w * 48 + nf * 16 + fr) * 1024 + fko];

    f32x4 acc[2][3];
    #pragma unroll
    for (int i = 0; i < 2; ++i)
        #pragma unroll
        for (int j = 0; j < 3; ++j) acc[i][j] = (f32x4){0.f, 0.f, 0.f, 0.f};

    // prologue: stage A for t=0
    {
        const float4 a0 = *reinterpret_cast<const float4*>(xrow);
        const float4 a1 = *reinterpret_cast<const float4*>(xrow + 4);
        *reinterpret_cast<uint4*>(&As[ar][ac]) =
            make_uint4(pack2(a0.x, a0.y), pack2(a0.z, a0.w),
                       pack2(a1.x, a1.y), pack2(a1.z, a1.w));
    }
    __syncthreads();

    for (int t = 0; t < 16; ++t) {
        // issue next A-tile loads early (independent of this step's compute)
        float4 n0, n1;
        if (t < 15) {
            n0 = *reinterpret_cast<const float4*>(xrow + (t + 1) * 64);
            n1 = *reinterpret_cast<const float4*>(xrow + (t + 1) * 64 + 4);
        }
        #pragma unroll
        for (int sub = 0; sub < 2; ++sub) {
            short8 af[2], bf[3];
            #pragma unroll
            for (int mf = 0; mf < 2; ++mf)
                af[mf] = *reinterpret_cast<const short8*>(
                    &As[mf * 16 + fr][sub * 32 + fko]);
            #pragma unroll
            for (int nf = 0; nf < 3; ++nf)
                bf[nf] = *reinterpret_cast<const short8*>(
                    &Brow[nf][t * 64 + sub * 32]);
            #pragma unroll
            for (int mf = 0; mf < 2; ++mf)
                #pragma unroll
                for (int nf = 0; nf < 3; ++nf)
                    acc[mf][nf] = __builtin_amdgcn_mfma_f32_16x16x32_bf16(
                        af[mf], bf[nf], acc[mf][nf], 0, 0, 0);
        }
        __syncthreads();                 // As consumed
        if (t < 15) {
            *reinterpret_cast<uint4*>(&As[ar][ac]) =
                make_uint4(pack2(n0.x, n0.y), pack2(n0.z, n0.w),
                           pack2(n1.x, n1.y), pack2(n1.z, n1.w));
        }
        __syncthreads();                 // As ready for t+1
    }

    // epilogue: C/D layout col=lane&15, row=fg*4+reg
    #pragma unroll
    for (int mf = 0; mf < 2; ++mf)
        #pragma unroll
        for (int nf = 0; nf < 3; ++nf) {
            const int col  = w * 48 + nf * 16 + fr;   // 0..191
            const int mat  = col >> 6;
            const int h    = col & 63;
            const int rowb = row0 + mf * 16 + (fg << 2);
            if (mat == 2) {
                // v -> vt[b][h][t], 4 consecutive t = one 8B store
                const int bb = rowb >> 11;
                const int t  = rowb & 2047;
                uint2 pk;
                pk.x = pack2(acc[mf][nf][0], acc[mf][nf][1]);
                pk.y = pack2(acc[mf][nf][2], acc[mf][nf][3]);
                *reinterpret_cast<uint2*>(&vt[((size_t)bb * 64 + h) * Tt + t]) = pk;
            } else {
                unsigned short* dst = mat ? kb : qb;
                #pragma unroll
                for (int r = 0; r < 4; ++r)
                    dst[(size_t)(rowb + r) * 64 + h] = f2bf(acc[mf][nf][r]);
            }
        }
}

// ---------------------------------------------------------------------------
// Kernel 3: causal flash attention, bf16 MFMA, swapped QK^T, Q-tile 16.
// Grid 1024 = 4 blocks/CU (4 waves/SIMD with launch_bounds(256,4)):
// b = fid&7 (batch per XCD, K/V/Q L2-resident), qt = 127-(fid>>3)
// (longest-first).  4 waves key-split (kt = w, w+4, ...), independent online
// softmax, LDS combine at end.  V-loads deferred past QK^T (VGPR peak cut);
// P packed with v_cvt_pk_bf16_f32; exact defer-max skip via __any.
// ---------------------------------------------------------------------------
__global__ __launch_bounds__(256, 4)
void attn_kernel(const unsigned short* __restrict__ qb,
                 const unsigned short* __restrict__ kb,
                 const unsigned short* __restrict__ vt,
                 float* __restrict__ out)
{
    __shared__ float smem[4608];                  // 18 KB union: Pw | (Om,Ms,Ls)

    const int tid  = threadIdx.x;
    const int fid  = blockIdx.x;
    const int b    = fid & 7;                     // XCD-matched batch
    const int qt   = 127 - (fid >> 3);            // longest-first, 0..127
    const int lane = tid & 63;
    const int w    = tid >> 6;                    // 0..3
    const int fr   = lane & 15;
    const int fg   = lane >> 4;                   // 0..3
    const int fko  = fg << 3;
    const int ktmax = qt >> 2;                    // last 64-key tile index

    // Q B-frags: lane holds qrow = qt*16+fr, h contiguous
    short8 aq[2];
    #pragma unroll
    for (int hs = 0; hs < 2; ++hs) {
        const size_t gq = (size_t)b * Tt + qt * 16 + fr;
        aq[hs] = *reinterpret_cast<const short8*>(&qb[gq * 64 + hs * 32 + fko]);
    }

    float mrun = -INFINITY, lrun = 0.f;
    f32x4 O[4];
    #pragma unroll
    for (int nh = 0; nh < 4; ++nh) O[nh] = (f32x4){0.f, 0.f, 0.f, 0.f};

    unsigned short* Pw = (unsigned short*)smem + w * 1152;   // [16][72] per wave

    for (int kt = w; kt <= ktmax; kt += 4) {
        // ---- K A-frags + QK^T (S^T: row=key=kf*16+fg*4+r, col=qrow=fr)
        const f32x4 zero = (f32x4){0.f, 0.f, 0.f, 0.f};
        f32x4 st[4];
        #pragma unroll
        for (int kf = 0; kf < 4; ++kf) {
            const size_t gk = (size_t)b * Tt + kt * 64 + kf * 16 + fr;
            const short8 k0 = *reinterpret_cast<const short8*>(&kb[gk * 64 + fko]);
            const short8 k1 = *reinterpret_cast<const short8*>(&kb[gk * 64 + 32 + fko]);
            f32x4 t = __builtin_amdgcn_mfma_f32_16x16x32_bf16(k0, aq[0], zero, 0, 0, 0);
            st[kf]  = __builtin_amdgcn_mfma_f32_16x16x32_bf16(k1, aq[1], t, 0, 0, 0);
        }

        // ---- V^T B-frags issued now: latency hides under softmax
        short8 bv[4][2];
        #pragma unroll
        for (int nh = 0; nh < 4; ++nh)
            #pragma unroll
            for (int ks = 0; ks < 2; ++ks) {
                const size_t gv = ((size_t)b * 64 + nh * 16 + fr) * Tt
                                  + kt * 64 + ks * 32 + fko;
                bv[nh][ks] = *reinterpret_cast<const short8*>(&vt[gv]);
            }

        // causal mask (diagonal tile only)
        if (kt == ktmax) {
            #pragma unroll
            for (int kf = 0; kf < 4; ++kf)
                #pragma unroll
                for (int r = 0; r < 4; ++r) {
                    const int key  = kt * 64 + kf * 16 + (fg << 2) + r;
                    const int qrow = qt * 16 + fr;
                    if (key > qrow) st[kf][r] = -INFINITY;
                }
        }

        // ---- online softmax, lane owns q-row fr (dup x4 across fg)
        float t0 = fmaxf(fmaxf(st[0][0], st[0][1]), fmaxf(st[0][2], st[0][3]));
        float t1 = fmaxf(fmaxf(st[1][0], st[1][1]), fmaxf(st[1][2], st[1][3]));
        float t2 = fmaxf(fmaxf(st[2][0], st[2][1]), fmaxf(st[2][2], st[2][3]));
        float t3 = fmaxf(fmaxf(st[3][0], st[3][1]), fmaxf(st[3][2], st[3][3]));
        float tmax = fmaxf(fmaxf(t0, t1), fmaxf(t2, t3));
        tmax = fmaxf(tmax, __shfl_xor(tmax, 16, 64));
        tmax = fmaxf(tmax, __shfl_xor(tmax, 32, 64));
        const float mn = fmaxf(mrun, tmax);
        if (__any(mn > mrun)) {                    // exact skip: else alpha==1
            const float al = exp2f(mrun - mn);     // -inf -> 0 on first tile
            float av[4];
            #pragma unroll
            for (int r = 0; r < 4; ++r)
                av[r] = __shfl(al, (fg << 2) + r, 64);
            const f32x4 avv = (f32x4){av[0], av[1], av[2], av[3]};
            #pragma unroll
            for (int nh = 0; nh < 4; ++nh) O[nh] *= avv;
            lrun *= al;
            mrun = mn;
        }
        float psum = 0.f;
        #pragma unroll
        for (int kf = 0; kf < 4; ++kf)
            #pragma unroll
            for (int r = 0; r < 4; ++r) {
                const float pv = exp2f(st[kf][r] - mrun);
                st[kf][r] = pv;
                psum += pv;
            }
        psum += __shfl_xor(psum, 16, 64);
        psum += __shfl_xor(psum, 32, 64);
        lrun += psum;

        // ---- P store: row=qrow fr, cols keys; one uint2 (b64) per kf
        #pragma unroll
        for (int kf = 0; kf < 4; ++kf) {
            uint2 pk;
            pk.x = pack2(st[kf][0], st[kf][1]);
            pk.y = pack2(st[kf][2], st[kf][3]);
            *reinterpret_cast<uint2*>(&Pw[fr * 72 + kf * 16 + (fg << 2)]) = pk;
        }

        // ---- PV: P A-frags (b128) x V^T B-frags
        short8 pa[2];
        #pragma unroll
        for (int ks = 0; ks < 2; ++ks)
            pa[ks] = *reinterpret_cast<const short8*>(&Pw[fr * 72 + ks * 32 + fko]);
        #pragma unroll
        for (int nh = 0; nh < 4; ++nh) {
            O[nh] = __builtin_amdgcn_mfma_f32_16x16x32_bf16(pa[0], bv[nh][0], O[nh], 0, 0, 0);
            O[nh] = __builtin_amdgcn_mfma_f32_16x16x32_bf16(pa[1], bv[nh][1], O[nh], 0, 0, 0);
        }
    }

    // ---- cross-wave combine (smem reused; waves' Pw all dead after barrier)
    __syncthreads();
    float* Om = smem;                      // [4][16][68]
    float* Ms = smem + 4352;               // [4][16]
    float* Ls = smem + 4416;               // [4][16]
    #pragma unroll
    for (int nh = 0; nh < 4; ++nh)
        #pragma unroll
        for (int r = 0; r < 4; ++r)
            Om[(w * 16 + (fg << 2) + r) * 68 + nh * 16 + fr] = O[nh][r];
    if (fg == 0) {
        Ms[w * 16 + fr] = mrun;
        Ls[w * 16 + fr] = lrun;
    }
    __syncthreads();

    const int row = tid >> 4;              // 0..15
    const int h0  = (tid & 15) << 2;       // 0..60
    float M = -INFINITY;
    #pragma unroll
    for (int ww = 0; ww < 4; ++ww) M = fmaxf(M, Ms[ww * 16 + row]);
    float L = 0.f;
    float4 o = make_float4(0.f, 0.f, 0.f, 0.f);
    #pragma unroll
    for (int ww = 0; ww < 4; ++ww) {
        const float sc = exp2f(Ms[ww * 16 + row] - M);   // idle wave: -inf -> 0
        L += Ls[ww * 16 + row] * sc;
        const float4 a = *reinterpret_cast<const float4*>(&Om[(ww * 16 + row) * 68 + h0]);
        o.x += a.x * sc; o.y += a.y * sc; o.z += a.z * sc; o.w += a.w * sc;
    }
    const float invL = 1.f / L;
    *reinterpret_cast<float4*>(&out[((size_t)b * Tt + qt * 16 + row) * 64 + h0]) =
        make_float4(o.x * invL, o.y * invL, o.z * invL, o.w * invL);
}

// ---------------------------------------------------------------------------
extern "C" void kernel_launch(void* const* d_in, const int* in_sizes, int n_in,
                              void* d_out, int out_size, void* d_ws, size_t ws_size,
                              hipStream_t stream)
{
    // setup_inputs order: x, Wk, Wq, Wv
    const float* x  = (const float*)d_in[0];
    const float* Wk = (const float*)d_in[1];
    const float* Wq = (const float*)d_in[2];
    const float* Wv = (const float*)d_in[3];
    float* out = (float*)d_out;

    const size_t n = (size_t)Bb * Tt * Hh;              // 1M elems per tensor
    unsigned short* WbT = (unsigned short*)d_ws;        // 192*1024
    unsigned short* qb  = WbT + 196608;
    unsigned short* kb  = qb + n;
    unsigned short* vt  = kb + n;                       // V^T [b][h][t]

    wconv_kernel<<<dim3(192),  256, 0, stream>>>(Wk, Wq, Wv, WbT);
    proj_kernel <<<dim3(512),  256, 0, stream>>>(x, WbT, qb, kb, vt);
    attn_kernel <<<dim3(1024), 256, 0, stream>>>(qb, kb, vt, out);
}

// Round 7
// 146.656 us; speedup vs baseline: 1.0997x; 1.0997x over previous
//
#include <hip/hip_runtime.h>
#include <math.h>

#define Bb 8
#define Tt 2048
#define Cc 1024
#define Hh 64

typedef __attribute__((ext_vector_type(8))) short short8;
typedef __attribute__((ext_vector_type(4))) float f32x4;

// float -> bf16 bits, round-to-nearest-even (scalar path)
static __device__ __forceinline__ unsigned short f2bf(float f) {
    union { float f; unsigned u; } v; v.f = f;
    return (unsigned short)((v.u + 0x7FFFu + ((v.u >> 16) & 1u)) >> 16);
}
// pack 2 f32 -> 2 bf16 in one instr (RNE, matches f2bf)
static __device__ __forceinline__ unsigned pack2(float lo, float hi) {
    unsigned r;
    asm("v_cvt_pk_bf16_f32 %0, %1, %2" : "=v"(r) : "v"(lo), "v"(hi));
    return r;
}

#define LOG2E 1.44269504088896340736f

// ---------------------------------------------------------------------------
// Kernel 1: W -> bf16, transposed [192][1024].  n 0-63 = Wq*(0.125*log2e),
// 64-127 = Wk, 128-191 = Wv.
// ---------------------------------------------------------------------------
__global__ __launch_bounds__(256)
void wconv_kernel(const float* __restrict__ Wk, const float* __restrict__ Wq,
                  const float* __restrict__ Wv, unsigned short* __restrict__ WbT)
{
    const int n = blockIdx.x;            // 0..191
    const int h = n & 63;
    const float* W; float scale = 1.0f;
    if (n < 64)       { W = Wq; scale = 0.125f * LOG2E; }
    else if (n < 128) { W = Wk; }
    else              { W = Wv; }
    #pragma unroll
    for (int i = 0; i < 4; ++i) {
        const int k = threadIdx.x + (i << 8);
        WbT[n * 1024 + k] = f2bf(W[k * 64 + h] * scale);
    }
}

// ---------------------------------------------------------------------------
// Kernel 2: QKV projection, bf16 MFMA, STAGE-ONCE / ZERO-BARRIER K-loop.
// [16384,1024] x [1024,192], tile 32(M) x 192(N), grid 512 (2 blocks/CU).
// The whole 32x1024 x-row-block is converted fp32->bf16 into LDS up front
// (stride 1040: b128 read & write patterns are uniform 8-lanes/window ->
// conflict-free), ONE barrier, then 16 K-steps of MFMA with A from LDS and
// wave-private B direct from L2 -- no barriers, compiler pipelines loads.
// v written transposed to vt[b][h][t] from the epilogue.
// ---------------------------------------------------------------------------
#define PK 1040
__global__ __launch_bounds__(256)
void proj_kernel(const float* __restrict__ x, const unsigned short* __restrict__ WbT,
                 unsigned short* __restrict__ qb, unsigned short* __restrict__ kb,
                 unsigned short* __restrict__ vt)
{
    __shared__ unsigned short As[32 * PK];       // 66.5 KB

    const int tid  = threadIdx.x;
    const int row0 = blockIdx.x * 32;
    const int lane = tid & 63;
    const int w    = tid >> 6;           // 0..3 -> N offset w*48
    const int fr   = lane & 15;
    const int fg   = lane >> 4;          // 0..3
    const int fko  = fg << 3;

    // ---- stage: 32 rows x 1024 cols fp32 -> bf16, 8 floats/thread/chunk
    {
        const int ar = tid >> 3;                  // 0..31
        const int ac = (tid & 7) << 3;            // 0..56
        const float* xrow = &x[(size_t)(row0 + ar) * Cc + ac];
        unsigned short* dstA = &As[ar * PK + ac];
        #pragma unroll
        for (int c = 0; c < 16; ++c) {
            const float4 a0 = *reinterpret_cast<const float4*>(xrow + c * 64);
            const float4 a1 = *reinterpret_cast<const float4*>(xrow + c * 64 + 4);
            *reinterpret_cast<uint4*>(dstA + c * 64) =
                make_uint4(pack2(a0.x, a0.y), pack2(a0.z, a0.w),
                           pack2(a1.x, a1.y), pack2(a1.z, a1.w));
        }
    }
    __syncthreads();                              // the ONLY barrier

    // B row bases (wave-private cols -> direct from L2)
    const unsigned short* Brow[3];
    #pragma unroll
    for (int nf = 0; nf < 3; ++nf)
        Brow[nf] = &WbT[(size_t)(w * 48 + nf * 16 + fr) * 1024 + fko];

    f32x4 acc[2][3];
    #pragma unroll
    for (int i = 0; i < 2; ++i)
        #pragma unroll
        for (int j = 0; j < 3; ++j) acc[i][j] = (f32x4){0.f, 0.f, 0.f, 0.f};

    #pragma unroll 4
    for (int t = 0; t < 16; ++t) {
        #pragma unroll
        for (int sub = 0; sub < 2; ++sub) {
            short8 af[2], bf[3];
            #pragma unroll
            for (int mf = 0; mf < 2; ++mf)
                af[mf] = *reinterpret_cast<const short8*>(
                    &As[(mf * 16 + fr) * PK + t * 64 + sub * 32 + fko]);
            #pragma unroll
            for (int nf = 0; nf < 3; ++nf)
                bf[nf] = *reinterpret_cast<const short8*>(
                    &Brow[nf][t * 64 + sub * 32]);
            #pragma unroll
            for (int mf = 0; mf < 2; ++mf)
                #pragma unroll
                for (int nf = 0; nf < 3; ++nf)
                    acc[mf][nf] = __builtin_amdgcn_mfma_f32_16x16x32_bf16(
                        af[mf], bf[nf], acc[mf][nf], 0, 0, 0);
        }
    }

    // epilogue: C/D layout col=lane&15, row=fg*4+reg
    #pragma unroll
    for (int mf = 0; mf < 2; ++mf)
        #pragma unroll
        for (int nf = 0; nf < 3; ++nf) {
            const int col  = w * 48 + nf * 16 + fr;   // 0..191
            const int mat  = col >> 6;
            const int h    = col & 63;
            const int rowb = row0 + mf * 16 + (fg << 2);
            if (mat == 2) {
                // v -> vt[b][h][t], 4 consecutive t = one 8B store
                const int bb = rowb >> 11;
                const int t  = rowb & 2047;
                uint2 pk;
                pk.x = pack2(acc[mf][nf][0], acc[mf][nf][1]);
                pk.y = pack2(acc[mf][nf][2], acc[mf][nf][3]);
                *reinterpret_cast<uint2*>(&vt[((size_t)bb * 64 + h) * Tt + t]) = pk;
            } else {
                unsigned short* dst = mat ? kb : qb;
                #pragma unroll
                for (int r = 0; r < 4; ++r)
                    dst[(size_t)(rowb + r) * 64 + h] = f2bf(acc[mf][nf][r]);
            }
        }
}

// ---------------------------------------------------------------------------
// Kernel 3: causal flash attention, bf16 MFMA, swapped QK^T, Q-tile 32,
// register double-buffered K-PREFETCH.
// Grid 512: b = fid&7 (batch per XCD, K/V/Q L2-resident), qt = 63-(fid>>3)
// (longest-first).  4 waves key-split (kt = w, w+4, ...), independent online
// softmax, LDS combine at end.  Pipeline per tile: issue next-K loads ->
// issue V loads -> QK MFMA (prev-loaded K) -> softmax (covers V latency) ->
// P bounce -> PV.  Loads always have >=1 softmax+PV phase of cover.
// ---------------------------------------------------------------------------
__global__ __launch_bounds__(256, 2)
void attn_kernel(const unsigned short* __restrict__ qb,
                 const unsigned short* __restrict__ kb,
                 const unsigned short* __restrict__ vt,
                 float* __restrict__ out)
{
    __shared__ float smem[9216];                  // 36 KB union: Pw | (Om,Ms,Ls)

    const int tid  = threadIdx.x;
    const int fid  = blockIdx.x;
    const int b    = fid & 7;                     // XCD-matched batch
    const int qt   = 63 - (fid >> 3);             // longest-first, 0..63
    const int lane = tid & 63;
    const int w    = tid >> 6;                    // 0..3
    const int fr   = lane & 15;
    const int fg   = lane >> 4;                   // 0..3
    const int fko  = fg << 3;
    const int ktmax = qt >> 1;

    // Q B-frags: lane holds qrow n*16+fr, h contiguous
    short8 aq[2][2];
    #pragma unroll
    for (int n = 0; n < 2; ++n)
        #pragma unroll
        for (int hs = 0; hs < 2; ++hs) {
            const size_t gq = (size_t)b * Tt + qt * 32 + n * 16 + fr;
            aq[n][hs] = *reinterpret_cast<const short8*>(&qb[gq * 64 + hs * 32 + fko]);
        }

    float mrun[2] = {-INFINITY, -INFINITY}, lrun[2] = {0.f, 0.f};
    f32x4 O[2][4];
    #pragma unroll
    for (int mf = 0; mf < 2; ++mf)
        #pragma unroll
        for (int nh = 0; nh < 4; ++nh) O[mf][nh] = (f32x4){0.f, 0.f, 0.f, 0.f};

    unsigned short* Pw = (unsigned short*)smem + w * 2304;   // [32][72] per wave

    // one K/V tile step; CUR holds K for `kt`, prefetches kt+4 into NXT
    auto body = [&](int kt, short8 (&CUR)[4][2], short8 (&NXT)[4][2]) {
        // ---- prefetch next K tile (clamped; discarded past the end)
        const int ktn = (kt + 4 <= ktmax) ? kt + 4 : ktmax;
        #pragma unroll
        for (int kf = 0; kf < 4; ++kf)
            #pragma unroll
            for (int hs = 0; hs < 2; ++hs) {
                const size_t gk = (size_t)b * Tt + ktn * 64 + kf * 16 + fr;
                NXT[kf][hs] = *reinterpret_cast<const short8*>(&kb[gk * 64 + hs * 32 + fko]);
            }
        // ---- V^T B-frags for current tile (latency covered by QK+softmax)
        short8 bv[4][2];
        #pragma unroll
        for (int nh = 0; nh < 4; ++nh)
            #pragma unroll
            for (int ks = 0; ks < 2; ++ks) {
                const size_t gv = ((size_t)b * 64 + nh * 16 + fr) * Tt
                                  + kt * 64 + ks * 32 + fko;
                bv[nh][ks] = *reinterpret_cast<const short8*>(&vt[gv]);
            }

        // ---- S^T = K Q^T : st[kf][n], row=key=kf*16+fg*4+r, col=qrow=n*16+fr
        const f32x4 zero = (f32x4){0.f, 0.f, 0.f, 0.f};
        f32x4 st[4][2];
        #pragma unroll
        for (int kf = 0; kf < 4; ++kf)
            #pragma unroll
            for (int n = 0; n < 2; ++n) {
                f32x4 t = __builtin_amdgcn_mfma_f32_16x16x32_bf16(CUR[kf][0], aq[n][0], zero, 0, 0, 0);
                st[kf][n] = __builtin_amdgcn_mfma_f32_16x16x32_bf16(CUR[kf][1], aq[n][1], t, 0, 0, 0);
            }

        // causal mask (diagonal tile only)
        if (kt == ktmax) {
            #pragma unroll
            for (int kf = 0; kf < 4; ++kf)
                #pragma unroll
                for (int n = 0; n < 2; ++n)
                    #pragma unroll
                    for (int r = 0; r < 4; ++r) {
                        const int key  = kt * 64 + kf * 16 + (fg << 2) + r;
                        const int qrow = qt * 32 + n * 16 + fr;
                        if (key > qrow) st[kf][n][r] = -INFINITY;
                    }
        }

        // ---- online softmax: lane owns q-rows n*16+fr (dup x4 across fg)
        float mn[2];
        #pragma unroll
        for (int n = 0; n < 2; ++n) {
            float tmax = -INFINITY;
            #pragma unroll
            for (int kf = 0; kf < 4; ++kf)
                #pragma unroll
                for (int r = 0; r < 4; ++r) tmax = fmaxf(tmax, st[kf][n][r]);
            tmax = fmaxf(tmax, __shfl_xor(tmax, 16, 64));
            tmax = fmaxf(tmax, __shfl_xor(tmax, 32, 64));
            mn[n] = fmaxf(mrun[n], tmax);
        }
        // exact defer-max: rescale only if some row's max grew
        if (__any((mn[0] > mrun[0]) | (mn[1] > mrun[1]))) {
            float alpha[2];
            #pragma unroll
            for (int n = 0; n < 2; ++n) {
                alpha[n] = exp2f(mrun[n] - mn[n]);   // -inf -> 0 first tile
                lrun[n] *= alpha[n];
                mrun[n] = mn[n];
            }
            #pragma unroll
            for (int mf = 0; mf < 2; ++mf) {
                f32x4 av;
                #pragma unroll
                for (int r = 0; r < 4; ++r)
                    av[r] = __shfl(alpha[mf], (fg << 2) + r, 64);
                #pragma unroll
                for (int nh = 0; nh < 4; ++nh) O[mf][nh] *= av;
            }
        }
        #pragma unroll
        for (int n = 0; n < 2; ++n) {
            float psum = 0.f;
            #pragma unroll
            for (int kf = 0; kf < 4; ++kf)
                #pragma unroll
                for (int r = 0; r < 4; ++r) {
                    const float pv = exp2f(st[kf][n][r] - mrun[n]);
                    st[kf][n][r] = pv;
                    psum += pv;
                }
            psum += __shfl_xor(psum, 16, 64);
            psum += __shfl_xor(psum, 32, 64);
            lrun[n] += psum;
        }

        // ---- P store: packed b64 per (kf,n)
        #pragma unroll
        for (int kf = 0; kf < 4; ++kf)
            #pragma unroll
            for (int n = 0; n < 2; ++n) {
                uint2 pk;
                pk.x = pack2(st[kf][n][0], st[kf][n][1]);
                pk.y = pack2(st[kf][n][2], st[kf][n][3]);
                *reinterpret_cast<uint2*>(
                    &Pw[(n * 16 + fr) * 72 + kf * 16 + (fg << 2)]) = pk;
            }

        // ---- PV: read P as A-frags (b128), MFMA with V^T B-frags
        short8 pa[2][2];
        #pragma unroll
        for (int mf = 0; mf < 2; ++mf)
            #pragma unroll
            for (int ks = 0; ks < 2; ++ks)
                pa[mf][ks] = *reinterpret_cast<const short8*>(
                    &Pw[(mf * 16 + fr) * 72 + ks * 32 + fko]);
        #pragma unroll
        for (int mf = 0; mf < 2; ++mf)
            #pragma unroll
            for (int nh = 0; nh < 4; ++nh) {
                O[mf][nh] = __builtin_amdgcn_mfma_f32_16x16x32_bf16(pa[mf][0], bv[nh][0], O[mf][nh], 0, 0, 0);
                O[mf][nh] = __builtin_amdgcn_mfma_f32_16x16x32_bf16(pa[mf][1], bv[nh][1], O[mf][nh], 0, 0, 0);
            }
    };

    short8 bkA[4][2], bkB[4][2];
    if (w <= ktmax) {
        #pragma unroll
        for (int kf = 0; kf < 4; ++kf)
            #pragma unroll
            for (int hs = 0; hs < 2; ++hs) {
                const size_t gk = (size_t)b * Tt + w * 64 + kf * 16 + fr;
                bkA[kf][hs] = *reinterpret_cast<const short8*>(&kb[gk * 64 + hs * 32 + fko]);
            }
        for (int kt = w; kt <= ktmax; kt += 8) {
            body(kt, bkA, bkB);
            if (kt + 4 <= ktmax) body(kt + 4, bkB, bkA);
        }
    }

    // ---- cross-wave combine
    __syncthreads();
    float* Om = smem;                      // [4][32][68]
    float* Ms = smem + 8704;               // [4][32]
    float* Ls = smem + 8832;               // [4][32]
    #pragma unroll
    for (int mf = 0; mf < 2; ++mf)
        #pragma unroll
        for (int nh = 0; nh < 4; ++nh)
            #pragma unroll
            for (int r = 0; r < 4; ++r)
                Om[(w * 32 + mf * 16 + (fg << 2) + r) * 68 + nh * 16 + fr] = O[mf][nh][r];
    if (fg == 0) {
        #pragma unroll
        for (int n = 0; n < 2; ++n) {
            Ms[w * 32 + n * 16 + fr] = mrun[n];
            Ls[w * 32 + n * 16 + fr] = lrun[n];
        }
    }
    __syncthreads();

    const int row = tid >> 3;              // 0..31
    const int h0  = (tid & 7) << 3;        // 0..56
    float M = -INFINITY;
    #pragma unroll
    for (int ww = 0; ww < 4; ++ww) M = fmaxf(M, Ms[ww * 32 + row]);
    float L = 0.f, o[8];
    #pragma unroll
    for (int j = 0; j < 8; ++j) o[j] = 0.f;
    #pragma unroll
    for (int ww = 0; ww < 4; ++ww) {
        const float sc = exp2f(Ms[ww * 32 + row] - M);   // idle wave: -inf -> 0
        L += Ls[ww * 32 + row] * sc;
        const float4 a = *reinterpret_cast<const float4*>(&Om[(ww * 32 + row) * 68 + h0]);
        const float4 c = *reinterpret_cast<const float4*>(&Om[(ww * 32 + row) * 68 + h0 + 4]);
        o[0] += a.x * sc; o[1] += a.y * sc; o[2] += a.z * sc; o[3] += a.w * sc;
        o[4] += c.x * sc; o[5] += c.y * sc; o[6] += c.z * sc; o[7] += c.w * sc;
    }
    const float invL = 1.f / L;
    float* dst = &out[((size_t)b * Tt + qt * 32 + row) * 64 + h0];
    *reinterpret_cast<float4*>(dst)     = make_float4(o[0]*invL, o[1]*invL, o[2]*invL, o[3]*invL);
    *reinterpret_cast<float4*>(dst + 4) = make_float4(o[4]*invL, o[5]*invL, o[6]*invL, o[7]*invL);
}

// ---------------------------------------------------------------------------
extern "C" void kernel_launch(void* const* d_in, const int* in_sizes, int n_in,
                              void* d_out, int out_size, void* d_ws, size_t ws_size,
                              hipStream_t stream)
{
    // setup_inputs order: x, Wk, Wq, Wv
    const float* x  = (const float*)d_in[0];
    const float* Wk = (const float*)d_in[1];
    const float* Wq = (const float*)d_in[2];
    const float* Wv = (const float*)d_in[3];
    float* out = (float*)d_out;

    const size_t n = (size_t)Bb * Tt * Hh;              // 1M elems per tensor
    unsigned short* WbT = (unsigned short*)d_ws;        // 192*1024
    unsigned short* qb  = WbT + 196608;
    unsigned short* kb  = qb + n;
    unsigned short* vt  = kb + n;                       // V^T [b][h][t]

    wconv_kernel<<<dim3(192), 256, 0, stream>>>(Wk, Wq, Wv, WbT);
    proj_kernel <<<dim3(512), 256, 0, stream>>>(x, WbT, qb, kb, vt);
    attn_kernel <<<dim3(512), 256, 0, stream>>>(qb, kb, vt, out);
}